// Round 4
// baseline (235.577 us; speedup 1.0000x reference)
//
#include <hip/hip_runtime.h>

#define BB 8
#define LL 2048
#define DD 256

typedef _Float16 half8 __attribute__((ext_vector_type(8)));
typedef float floatx4 __attribute__((ext_vector_type(4)));
typedef unsigned short ushort8 __attribute__((ext_vector_type(8)));

__device__ inline unsigned short f2h(float f) {
  _Float16 h = (_Float16)f;
  return __builtin_bit_cast(unsigned short, h);
}

#define GLD16(src, ldsbase)                                                    \
  __builtin_amdgcn_global_load_lds(                                           \
      (const __attribute__((address_space(1))) unsigned int*)(src),           \
      (__attribute__((address_space(3))) unsigned int*)(ldsbase), 16, 0, 0)

// ---------------------------------------------------------------------------
// Kernel 0: W fp32 -> fp16, Wh[3][256][256].  grid 96, block 256.
// ---------------------------------------------------------------------------
__global__ __launch_bounds__(256) void wcvt(
    const float* __restrict__ Wq, const float* __restrict__ Wk,
    const float* __restrict__ Wv, unsigned short* __restrict__ Wh) {
  const int bm = blockIdx.x >> 5;
  const float* src = (bm == 0) ? Wq : (bm == 1) ? Wk : Wv;
  const int off = (blockIdx.x & 31) * 2048 + threadIdx.x * 8;
  float4 a = *(const float4*)(src + off);
  float4 b = *(const float4*)(src + off + 4);
  ushort8 u = {f2h(a.x), f2h(a.y), f2h(a.z), f2h(a.w),
               f2h(b.x), f2h(b.y), f2h(b.z), f2h(b.w)};
  *(ushort8*)(Wh + bm * 65536 + off) = u;
}

// ---------------------------------------------------------------------------
// Kernel 1: fused QKV projection (unchanged this round).
// ---------------------------------------------------------------------------
__global__ __launch_bounds__(256) void proj(
    const float* __restrict__ x, const unsigned short* __restrict__ Wh,
    unsigned short* __restrict__ Qb, unsigned short* __restrict__ Kb,
    unsigned short* __restrict__ VT) {
  __shared__ __attribute__((aligned(16))) unsigned short tile[10240];
  const int t = threadIdx.x;
  const int wave = t >> 6, lane = t & 63, quad = lane >> 4, m16 = lane & 15;
  const int l0g = blockIdx.x * 32;
  const int b = l0g >> 11, lb = l0g & 2047;

  half8 xf[2][8];
  for (int mt = 0; mt < 2; ++mt) {
    const float* xp = x + (size_t)(l0g + mt * 16 + m16) * DD + quad * 8;
    for (int kb = 0; kb < 8; ++kb) {
      float4 a = *(const float4*)(xp + kb * 32);
      float4 c = *(const float4*)(xp + kb * 32 + 4);
      ushort8 u = {f2h(a.x), f2h(a.y), f2h(a.z), f2h(a.w),
                   f2h(c.x), f2h(c.y), f2h(c.z), f2h(c.w)};
      xf[mt][kb] = __builtin_bit_cast(half8, u);
    }
  }

  for (int mat = 0; mat < 3; ++mat) {
    for (int j = 0; j < 4; ++j) {
      const int ot = wave * 4 + j;
      const unsigned short* wp =
          Wh + mat * 65536 + (ot * 16 + m16) * DD + quad * 8;
      floatx4 acc[2] = {{0, 0, 0, 0}, {0, 0, 0, 0}};
      if (mat < 2) {
        for (int kb = 0; kb < 8; ++kb) {
          half8 wf =
              __builtin_bit_cast(half8, *(const ushort8*)(wp + kb * 32));
          acc[0] = __builtin_amdgcn_mfma_f32_16x16x32_f16(xf[0][kb], wf,
                                                          acc[0], 0, 0, 0);
          acc[1] = __builtin_amdgcn_mfma_f32_16x16x32_f16(xf[1][kb], wf,
                                                          acc[1], 0, 0, 0);
        }
        for (int mt = 0; mt < 2; ++mt)
          for (int r = 0; r < 4; ++r)
            tile[(mt * 16 + quad * 4 + r) * 264 + ot * 16 + m16] =
                f2h(acc[mt][r]);
      } else {
        for (int kb = 0; kb < 8; ++kb) {
          half8 wf =
              __builtin_bit_cast(half8, *(const ushort8*)(wp + kb * 32));
          acc[0] = __builtin_amdgcn_mfma_f32_16x16x32_f16(wf, xf[0][kb],
                                                          acc[0], 0, 0, 0);
          acc[1] = __builtin_amdgcn_mfma_f32_16x16x32_f16(wf, xf[1][kb],
                                                          acc[1], 0, 0, 0);
        }
        for (int mt = 0; mt < 2; ++mt)
          for (int r = 0; r < 4; ++r)
            tile[(ot * 16 + quad * 4 + r) * 40 + mt * 16 + m16] =
                f2h(acc[mt][r]);
      }
    }
    __syncthreads();
    if (mat < 2) {
      unsigned short* Out = mat ? Kb : Qb;
      const int row = t >> 3, c0 = (t & 7) * 8;
      for (int i = 0; i < 4; ++i) {
        ushort8 v = *(const ushort8*)&tile[row * 264 + c0 + i * 64];
        *(ushort8*)(Out + (size_t)(l0g + row) * DD + c0 + i * 64) = v;
      }
    } else {
      const int dd = t >> 2, lc = (t & 3) * 8;
      for (int p = 0; p < 4; ++p) {
        const int d = p * 64 + dd;
        ushort8 v = *(const ushort8*)&tile[d * 40 + lc];
        *(ushort8*)(VT + ((size_t)(b * DD + d)) * LL + lb + lc) = v;
      }
    }
    __syncthreads();
  }
}

// ---------------------------------------------------------------------------
// Kernel 2: flash attention.  512 thr = 8 waves = 2 qw-groups x 4 kv-grps.
// Each wave owns 32 q-rows (2 m-tiles) -> every K/V fragment feeds 2 MFMAs
// (halves LDS read volume).  kv split 4-way across grps (32 kv each),
// 4-way online-softmax merge at the end.
// Staging: global_load_lds w/ pre-swizzled source, linear LDS dest.
// NOTE: min-waves MUST be 1: per-thread state ~240 VGPR; (512,2) caps at
// 128 and spills the whole O accumulator to scratch (round-2 regression:
// WRITE_SIZE doubled, 5x slowdown).  Grid is 256 blocks on 256 CUs, so
// 1 block/CU is what we get anyway.
// ---------------------------------------------------------------------------
__global__ __launch_bounds__(512, 1) void attn(
    const unsigned short* __restrict__ Qb, const unsigned short* __restrict__ Kb,
    const unsigned short* __restrict__ VT, const int* __restrict__ lens,
    float* __restrict__ out) {
  // [0,65536)      Ks: 4 grps x [32 kv][256 d]   (16B chunk cc ^ (row&7))
  // [65536,131072) Vs: 4 grps x [256 d][32 kv]   (16B chunk cv ^ ((d>>1)&3))
  // [131072,151552) Pw: 8 waves x [32 q][40 hw]
  __shared__ __attribute__((aligned(16))) unsigned char smem[151552];
  const int t = threadIdx.x;
  const int wave = t >> 6, lane = t & 63, quad = lane >> 4, m16 = lane & 15;
  const int qw = wave >> 2, grp = wave & 3;
  unsigned short* Ks = (unsigned short*)(smem + grp * 16384);
  unsigned short* Vs = (unsigned short*)(smem + 65536 + grp * 16384);
  unsigned short* Pw = (unsigned short*)(smem + 131072 + wave * 2560);

  const int b = blockIdx.x;  // batch on x -> XCD L2 affinity
  const int q0 = blockIdx.y * 64 + qw * 32;
  const int len = lens[b];
  const size_t baseQK = (size_t)b * LL * DD;
  const size_t baseVT = (size_t)b * DD * LL;
  const unsigned short* kbase = Kb + baseQK;
  const unsigned short* vbase = VT + baseVT;

  half8 qf[2][8];
  for (int mt = 0; mt < 2; ++mt) {
    const unsigned short* qrow =
        Qb + baseQK + (size_t)(q0 + mt * 16 + m16) * DD + quad * 8;
    for (int kb = 0; kb < 8; ++kb)
      qf[mt][kb] = __builtin_bit_cast(half8, *(const ushort8*)(qrow + kb * 32));
  }

  floatx4 O[2][16];
  for (int mt = 0; mt < 2; ++mt)
    for (int i = 0; i < 16; ++i) O[mt][i] = (floatx4){0, 0, 0, 0};
  float mrow[2][4], lrow[2][4];
  for (int mt = 0; mt < 2; ++mt)
    for (int r = 0; r < 4; ++r) {
      mrow[mt][r] = -1e30f;
      lrow[mt][r] = 0.f;
    }

// K tile: 4096 chunks (4 grps x 1024); chunk idx -> grp(idx>>10),
// row(ch>>5), cc(ch&31); LDS byte = idx*16 (linear); source pre-swizzled.
#define STAGE_K(KV0)                                                          \
  for (int c = 0; c < 8; ++c) {                                               \
    int idx = c * 512 + t;                                                    \
    int gs = idx >> 10, ch = idx & 1023, row = ch >> 5, cc = ch & 31;         \
    const unsigned short* src = kbase +                                       \
        (size_t)((KV0) + gs * 32 + row) * DD + ((cc ^ (row & 7)) << 3);       \
    GLD16(src, smem + (c * 512 + wave * 64) * 16);                            \
  }
#define STAGE_V(KV0)                                                          \
  for (int c = 0; c < 8; ++c) {                                               \
    int idx = c * 512 + t;                                                    \
    int gs = idx >> 10, ch = idx & 1023, d = ch >> 2, cv = ch & 3;            \
    const unsigned short* src = vbase + (size_t)d * LL + (KV0) + gs * 32 +    \
                                ((cv ^ ((d >> 1) & 3)) << 3);                 \
    GLD16(src, smem + 65536 + (c * 512 + wave * 64) * 16);                    \
  }

  const int T = (len + 127) >> 7;  // 128 kv per block-iter (4 grps x 32)
  STAGE_K(0);
  STAGE_V(0);
  __syncthreads();  // drains DMA (syncthreads waits vmcnt(0))

  for (int it = 0; it < T; ++it) {
    const int kv0 = it * 128;
    const int kvg = kv0 + grp * 32;
    const bool active = kvg < len;
    const bool more = (it + 1) < T;

    floatx4 s[2][2];
    if (active) {
      for (int mt = 0; mt < 2; ++mt)
        for (int n = 0; n < 2; ++n) s[mt][n] = (floatx4){0, 0, 0, 0};
      __builtin_amdgcn_s_setprio(1);
      for (int kb = 0; kb < 8; ++kb)
        for (int n = 0; n < 2; ++n) {
          half8 kf = __builtin_bit_cast(
              half8, *(const ushort8*)&Ks[(n * 16 + m16) * 256 +
                                          (((kb * 4 + quad) ^ (m16 & 7)) << 3)]);
          s[0][n] = __builtin_amdgcn_mfma_f32_16x16x32_f16(qf[0][kb], kf,
                                                           s[0][n], 0, 0, 0);
          s[1][n] = __builtin_amdgcn_mfma_f32_16x16x32_f16(qf[1][kb], kf,
                                                           s[1][n], 0, 0, 0);
        }
      __builtin_amdgcn_s_setprio(0);
    }
    __syncthreads();  // all K reads done
    if (more) STAGE_K(kv0 + 128);  // K refill hides under softmax+PV

    if (active) {
      float sv[2][2][4];
      bool vld[2];
      for (int n = 0; n < 2; ++n) vld[n] = (kvg + n * 16 + m16) < len;
      for (int mt = 0; mt < 2; ++mt)
        for (int n = 0; n < 2; ++n)
          for (int r = 0; r < 4; ++r)
            sv[mt][n][r] = vld[n] ? s[mt][n][r] * 0.0625f : -1e30f;
      float alv[2][4];
      for (int mt = 0; mt < 2; ++mt)
        for (int r = 0; r < 4; ++r) {
          float v = fmaxf(sv[mt][0][r], sv[mt][1][r]);
          v = fmaxf(v, __shfl_xor(v, 1));
          v = fmaxf(v, __shfl_xor(v, 2));
          v = fmaxf(v, __shfl_xor(v, 4));
          v = fmaxf(v, __shfl_xor(v, 8));
          float mn = fmaxf(mrow[mt][r], v);
          float al = __expf(mrow[mt][r] - mn);
          mrow[mt][r] = mn;
          float sum = 0.f;
          for (int n = 0; n < 2; ++n) {
            float p = __expf(sv[mt][n][r] - mn);
            Pw[(mt * 16 + quad * 4 + r) * 40 + n * 16 + m16] = f2h(p);
            sum += p;
          }
          sum += __shfl_xor(sum, 1);
          sum += __shfl_xor(sum, 2);
          sum += __shfl_xor(sum, 4);
          sum += __shfl_xor(sum, 8);
          lrow[mt][r] = lrow[mt][r] * al + sum;
          alv[mt][r] = al;
        }
      for (int mt = 0; mt < 2; ++mt)
        for (int nb = 0; nb < 16; ++nb)
          for (int r = 0; r < 4; ++r) O[mt][nb][r] *= alv[mt][r];
      half8 pf[2];
      for (int mt = 0; mt < 2; ++mt)
        pf[mt] = __builtin_bit_cast(
            half8, *(const ushort8*)&Pw[(mt * 16 + m16) * 40 + quad * 8]);
      __builtin_amdgcn_s_setprio(1);
      for (int nb = 0; nb < 16; ++nb) {
        const int d = nb * 16 + m16;
        half8 vf = __builtin_bit_cast(
            half8,
            *(const ushort8*)&Vs[d * 32 + ((quad ^ ((d >> 1) & 3)) << 3)]);
        O[0][nb] = __builtin_amdgcn_mfma_f32_16x16x32_f16(pf[0], vf, O[0][nb],
                                                          0, 0, 0);
        O[1][nb] = __builtin_amdgcn_mfma_f32_16x16x32_f16(pf[1], vf, O[1][nb],
                                                          0, 0, 0);
      }
      __builtin_amdgcn_s_setprio(0);
    }
    __syncthreads();  // all V reads done (also drains K DMAs, ~free)
    if (more) STAGE_V(kv0 + 128);
    __syncthreads();  // drains V DMAs
  }
#undef STAGE_K
#undef STAGE_V

  // ---- 4-way merge: (grp2,grp3) -> (grp0,grp1), then grp1 -> grp0 ----
  __syncthreads();
  float* OmB = (float*)smem;               // 4 slots x 32x257 f32
  float* mlB = (float*)(smem + 131584);    // 4 slots x 32 x {m,l}
  if (grp >= 2) {
    const int slot = (grp & 1) + 2 * qw;
    float* Om = OmB + slot * 8224;
    float* ml = mlB + slot * 64;
    for (int mt = 0; mt < 2; ++mt)
      for (int nb = 0; nb < 16; ++nb)
        for (int r = 0; r < 4; ++r)
          Om[(mt * 16 + quad * 4 + r) * 257 + nb * 16 + m16] = O[mt][nb][r];
    if (m16 == 0)
      for (int mt = 0; mt < 2; ++mt)
        for (int r = 0; r < 4; ++r) {
          ml[(mt * 16 + quad * 4 + r) * 2] = mrow[mt][r];
          ml[(mt * 16 + quad * 4 + r) * 2 + 1] = lrow[mt][r];
        }
  }
  __syncthreads();
  if (grp < 2) {
    const int slot = grp + 2 * qw;
    float* Om = OmB + slot * 8224;
    float* ml = mlB + slot * 64;
    float av[2][4], bv[2][4];
    for (int mt = 0; mt < 2; ++mt)
      for (int r = 0; r < 4; ++r) {
        const int row = mt * 16 + quad * 4 + r;
        float mB = ml[row * 2], lB = ml[row * 2 + 1];
        float m = fmaxf(mrow[mt][r], mB);
        float a = __expf(mrow[mt][r] - m);
        float bb = __expf(mB - m);
        lrow[mt][r] = lrow[mt][r] * a + lB * bb;
        mrow[mt][r] = m;
        av[mt][r] = a;
        bv[mt][r] = bb;
      }
    for (int mt = 0; mt < 2; ++mt)
      for (int nb = 0; nb < 16; ++nb)
        for (int r = 0; r < 4; ++r)
          O[mt][nb][r] =
              O[mt][nb][r] * av[mt][r] +
              Om[(mt * 16 + quad * 4 + r) * 257 + nb * 16 + m16] * bv[mt][r];
  }
  __syncthreads();
  if (grp == 1) {
    const int slot = qw;
    float* Om = OmB + slot * 8224;
    float* ml = mlB + slot * 64;
    for (int mt = 0; mt < 2; ++mt)
      for (int nb = 0; nb < 16; ++nb)
        for (int r = 0; r < 4; ++r)
          Om[(mt * 16 + quad * 4 + r) * 257 + nb * 16 + m16] = O[mt][nb][r];
    if (m16 == 0)
      for (int mt = 0; mt < 2; ++mt)
        for (int r = 0; r < 4; ++r) {
          ml[(mt * 16 + quad * 4 + r) * 2] = mrow[mt][r];
          ml[(mt * 16 + quad * 4 + r) * 2 + 1] = lrow[mt][r];
        }
  }
  __syncthreads();
  if (grp == 0) {
    const int slot = qw;
    float* Om = OmB + slot * 8224;
    float* ml = mlB + slot * 64;
    float av[2][4], bv[2][4], inv[2][4];
    for (int mt = 0; mt < 2; ++mt)
      for (int r = 0; r < 4; ++r) {
        const int row = mt * 16 + quad * 4 + r;
        float mB = ml[row * 2], lB = ml[row * 2 + 1];
        float m = fmaxf(mrow[mt][r], mB);
        float a = __expf(mrow[mt][r] - m);
        float bb = __expf(mB - m);
        av[mt][r] = a;
        bv[mt][r] = bb;
        inv[mt][r] = 1.f / (lrow[mt][r] * a + lB * bb);
      }
    for (int mt = 0; mt < 2; ++mt)
      for (int nb = 0; nb < 16; ++nb)
        for (int r = 0; r < 4; ++r) {
          float ob = Om[(mt * 16 + quad * 4 + r) * 257 + nb * 16 + m16];
          out[baseQK + (size_t)(q0 + mt * 16 + quad * 4 + r) * DD + nb * 16 +
              m16] = (O[mt][nb][r] * av[mt][r] + ob * bv[mt][r]) * inv[mt][r];
        }
  }
}

extern "C" void kernel_launch(void* const* d_in, const int* in_sizes, int n_in,
                              void* d_out, int out_size, void* d_ws, size_t ws_size,
                              hipStream_t stream) {
  const float* x = (const float*)d_in[0];
  const float* Wq = (const float*)d_in[1];
  const float* Wk = (const float*)d_in[2];
  const float* Wv = (const float*)d_in[3];
  const int* lens = (const int*)d_in[4];
  unsigned short* Qb = (unsigned short*)d_ws;
  unsigned short* Kb = Qb + (size_t)BB * LL * DD;
  unsigned short* VT = Kb + (size_t)BB * LL * DD;
  unsigned short* Wh = VT + (size_t)BB * LL * DD;
  float* out = (float*)d_out;

  wcvt<<<96, 256, 0, stream>>>(Wq, Wk, Wv, Wh);
  proj<<<512, 256, 0, stream>>>(x, Wh, Qb, Kb, VT);
  attn<<<dim3(8, 32), 512, 0, stream>>>(Qb, Kb, VT, lens, out);
}

// Round 5
// 233.680 us; speedup vs baseline: 1.0081x; 1.0081x over previous
//
#include <hip/hip_runtime.h>

#define BB 8
#define LL 2048
#define DD 256

typedef _Float16 half8 __attribute__((ext_vector_type(8)));
typedef float floatx4 __attribute__((ext_vector_type(4)));
typedef unsigned short ushort8 __attribute__((ext_vector_type(8)));

__device__ inline unsigned short f2h(float f) {
  _Float16 h = (_Float16)f;
  return __builtin_bit_cast(unsigned short, h);
}

#define GLD16(src, ldsbase)                                                    \
  __builtin_amdgcn_global_load_lds(                                           \
      (const __attribute__((address_space(1))) unsigned int*)(src),           \
      (__attribute__((address_space(3))) unsigned int*)(ldsbase), 16, 0, 0)

// ---------------------------------------------------------------------------
// Kernel 0: W fp32 -> fp16, Wh[3][256][256].  grid 96, block 256.
// ---------------------------------------------------------------------------
__global__ __launch_bounds__(256) void wcvt(
    const float* __restrict__ Wq, const float* __restrict__ Wk,
    const float* __restrict__ Wv, unsigned short* __restrict__ Wh) {
  const int bm = blockIdx.x >> 5;
  const float* src = (bm == 0) ? Wq : (bm == 1) ? Wk : Wv;
  const int off = (blockIdx.x & 31) * 2048 + threadIdx.x * 8;
  float4 a = *(const float4*)(src + off);
  float4 b = *(const float4*)(src + off + 4);
  ushort8 u = {f2h(a.x), f2h(a.y), f2h(a.z), f2h(a.w),
               f2h(b.x), f2h(b.y), f2h(b.z), f2h(b.w)};
  *(ushort8*)(Wh + bm * 65536 + off) = u;
}

// ---------------------------------------------------------------------------
// Kernel 1: fused QKV projection (unchanged this round).
// ---------------------------------------------------------------------------
__global__ __launch_bounds__(256) void proj(
    const float* __restrict__ x, const unsigned short* __restrict__ Wh,
    unsigned short* __restrict__ Qb, unsigned short* __restrict__ Kb,
    unsigned short* __restrict__ VT) {
  __shared__ __attribute__((aligned(16))) unsigned short tile[10240];
  const int t = threadIdx.x;
  const int wave = t >> 6, lane = t & 63, quad = lane >> 4, m16 = lane & 15;
  const int l0g = blockIdx.x * 32;
  const int b = l0g >> 11, lb = l0g & 2047;

  half8 xf[2][8];
#pragma unroll
  for (int mt = 0; mt < 2; ++mt) {
    const float* xp = x + (size_t)(l0g + mt * 16 + m16) * DD + quad * 8;
#pragma unroll
    for (int kb = 0; kb < 8; ++kb) {
      float4 a = *(const float4*)(xp + kb * 32);
      float4 c = *(const float4*)(xp + kb * 32 + 4);
      ushort8 u = {f2h(a.x), f2h(a.y), f2h(a.z), f2h(a.w),
                   f2h(c.x), f2h(c.y), f2h(c.z), f2h(c.w)};
      xf[mt][kb] = __builtin_bit_cast(half8, u);
    }
  }

  for (int mat = 0; mat < 3; ++mat) {
#pragma unroll
    for (int j = 0; j < 4; ++j) {
      const int ot = wave * 4 + j;
      const unsigned short* wp =
          Wh + mat * 65536 + (ot * 16 + m16) * DD + quad * 8;
      floatx4 acc[2] = {{0, 0, 0, 0}, {0, 0, 0, 0}};
      if (mat < 2) {
#pragma unroll
        for (int kb = 0; kb < 8; ++kb) {
          half8 wf =
              __builtin_bit_cast(half8, *(const ushort8*)(wp + kb * 32));
          acc[0] = __builtin_amdgcn_mfma_f32_16x16x32_f16(xf[0][kb], wf,
                                                          acc[0], 0, 0, 0);
          acc[1] = __builtin_amdgcn_mfma_f32_16x16x32_f16(xf[1][kb], wf,
                                                          acc[1], 0, 0, 0);
        }
#pragma unroll
        for (int mt = 0; mt < 2; ++mt)
#pragma unroll
          for (int r = 0; r < 4; ++r)
            tile[(mt * 16 + quad * 4 + r) * 264 + ot * 16 + m16] =
                f2h(acc[mt][r]);
      } else {
#pragma unroll
        for (int kb = 0; kb < 8; ++kb) {
          half8 wf =
              __builtin_bit_cast(half8, *(const ushort8*)(wp + kb * 32));
          acc[0] = __builtin_amdgcn_mfma_f32_16x16x32_f16(wf, xf[0][kb],
                                                          acc[0], 0, 0, 0);
          acc[1] = __builtin_amdgcn_mfma_f32_16x16x32_f16(wf, xf[1][kb],
                                                          acc[1], 0, 0, 0);
        }
#pragma unroll
        for (int mt = 0; mt < 2; ++mt)
#pragma unroll
          for (int r = 0; r < 4; ++r)
            tile[(ot * 16 + quad * 4 + r) * 40 + mt * 16 + m16] =
                f2h(acc[mt][r]);
      }
    }
    __syncthreads();
    if (mat < 2) {
      unsigned short* Out = mat ? Kb : Qb;
      const int row = t >> 3, c0 = (t & 7) * 8;
#pragma unroll
      for (int i = 0; i < 4; ++i) {
        ushort8 v = *(const ushort8*)&tile[row * 264 + c0 + i * 64];
        *(ushort8*)(Out + (size_t)(l0g + row) * DD + c0 + i * 64) = v;
      }
    } else {
      const int dd = t >> 2, lc = (t & 3) * 8;
#pragma unroll
      for (int p = 0; p < 4; ++p) {
        const int d = p * 64 + dd;
        ushort8 v = *(const ushort8*)&tile[d * 40 + lc];
        *(ushort8*)(VT + ((size_t)(b * DD + d)) * LL + lb + lc) = v;
      }
    }
    __syncthreads();
  }
}

// ---------------------------------------------------------------------------
// Kernel 2: flash attention.  512 thr = 8 waves = 2 qw-groups x 4 kv-grps.
// Each wave owns 32 q-rows (2 m-tiles); kv split 4-way across grps.
// ALL register-array loops carry #pragma unroll: without it the compiler
// leaves nb runtime -> O[2][16] lands in scratch (rule #20; round-3/4
// regression: VGPR=128 + 17MB scratch writes per dispatch).
// ---------------------------------------------------------------------------
__global__ __launch_bounds__(512, 1) void attn(
    const unsigned short* __restrict__ Qb, const unsigned short* __restrict__ Kb,
    const unsigned short* __restrict__ VT, const int* __restrict__ lens,
    float* __restrict__ out) {
  // [0,65536)      Ks: 4 grps x [32 kv][256 d]   (16B chunk cc ^ (row&7))
  // [65536,131072) Vs: 4 grps x [256 d][32 kv]   (16B chunk cv ^ ((d>>1)&3))
  // [131072,151552) Pw: 8 waves x [32 q][40 hw]
  __shared__ __attribute__((aligned(16))) unsigned char smem[151552];
  const int t = threadIdx.x;
  const int wave = t >> 6, lane = t & 63, quad = lane >> 4, m16 = lane & 15;
  const int qw = wave >> 2, grp = wave & 3;
  unsigned short* Ks = (unsigned short*)(smem + grp * 16384);
  unsigned short* Vs = (unsigned short*)(smem + 65536 + grp * 16384);
  unsigned short* Pw = (unsigned short*)(smem + 131072 + wave * 2560);

  const int b = blockIdx.x;  // batch on x -> XCD L2 affinity
  const int q0 = blockIdx.y * 64 + qw * 32;
  const int len = lens[b];
  const size_t baseQK = (size_t)b * LL * DD;
  const size_t baseVT = (size_t)b * DD * LL;
  const unsigned short* kbase = Kb + baseQK;
  const unsigned short* vbase = VT + baseVT;

  half8 qf[2][8];
#pragma unroll
  for (int mt = 0; mt < 2; ++mt) {
    const unsigned short* qrow =
        Qb + baseQK + (size_t)(q0 + mt * 16 + m16) * DD + quad * 8;
#pragma unroll
    for (int kb = 0; kb < 8; ++kb)
      qf[mt][kb] = __builtin_bit_cast(half8, *(const ushort8*)(qrow + kb * 32));
  }

  floatx4 O[2][16];
#pragma unroll
  for (int mt = 0; mt < 2; ++mt)
#pragma unroll
    for (int i = 0; i < 16; ++i) O[mt][i] = (floatx4){0, 0, 0, 0};
  float mrow[2][4], lrow[2][4];
#pragma unroll
  for (int mt = 0; mt < 2; ++mt)
#pragma unroll
    for (int r = 0; r < 4; ++r) {
      mrow[mt][r] = -1e30f;
      lrow[mt][r] = 0.f;
    }

// K tile: 4096 chunks (4 grps x 1024); chunk idx -> grp(idx>>10),
// row(ch>>5), cc(ch&31); LDS byte = idx*16 (linear); source pre-swizzled.
#define STAGE_K(KV0)                                                          \
  _Pragma("unroll") for (int c = 0; c < 8; ++c) {                             \
    int idx = c * 512 + t;                                                    \
    int gs = idx >> 10, ch = idx & 1023, row = ch >> 5, cc = ch & 31;         \
    const unsigned short* src = kbase +                                       \
        (size_t)((KV0) + gs * 32 + row) * DD + ((cc ^ (row & 7)) << 3);       \
    GLD16(src, smem + (c * 512 + wave * 64) * 16);                            \
  }
#define STAGE_V(KV0)                                                          \
  _Pragma("unroll") for (int c = 0; c < 8; ++c) {                             \
    int idx = c * 512 + t;                                                    \
    int gs = idx >> 10, ch = idx & 1023, d = ch >> 2, cv = ch & 3;            \
    const unsigned short* src = vbase + (size_t)d * LL + (KV0) + gs * 32 +    \
                                ((cv ^ ((d >> 1) & 3)) << 3);                 \
    GLD16(src, smem + 65536 + (c * 512 + wave * 64) * 16);                    \
  }

  const int T = (len + 127) >> 7;  // 128 kv per block-iter (4 grps x 32)
  STAGE_K(0);
  STAGE_V(0);
  __syncthreads();  // drains DMA

  for (int it = 0; it < T; ++it) {
    const int kv0 = it * 128;
    const int kvg = kv0 + grp * 32;
    const bool active = kvg < len;
    const bool more = (it + 1) < T;

    floatx4 s[2][2];
    if (active) {
#pragma unroll
      for (int mt = 0; mt < 2; ++mt)
#pragma unroll
        for (int n = 0; n < 2; ++n) s[mt][n] = (floatx4){0, 0, 0, 0};
      __builtin_amdgcn_s_setprio(1);
#pragma unroll
      for (int kb = 0; kb < 8; ++kb)
#pragma unroll
        for (int n = 0; n < 2; ++n) {
          half8 kf = __builtin_bit_cast(
              half8, *(const ushort8*)&Ks[(n * 16 + m16) * 256 +
                                          (((kb * 4 + quad) ^ (m16 & 7)) << 3)]);
          s[0][n] = __builtin_amdgcn_mfma_f32_16x16x32_f16(qf[0][kb], kf,
                                                           s[0][n], 0, 0, 0);
          s[1][n] = __builtin_amdgcn_mfma_f32_16x16x32_f16(qf[1][kb], kf,
                                                           s[1][n], 0, 0, 0);
        }
      __builtin_amdgcn_s_setprio(0);
    }
    __syncthreads();  // all K reads done
    if (more) STAGE_K(kv0 + 128);  // K refill hides under softmax+PV

    if (active) {
      float sv[2][2][4];
      bool vld[2];
#pragma unroll
      for (int n = 0; n < 2; ++n) vld[n] = (kvg + n * 16 + m16) < len;
#pragma unroll
      for (int mt = 0; mt < 2; ++mt)
#pragma unroll
        for (int n = 0; n < 2; ++n)
#pragma unroll
          for (int r = 0; r < 4; ++r)
            sv[mt][n][r] = vld[n] ? s[mt][n][r] * 0.0625f : -1e30f;
      float alv[2][4];
#pragma unroll
      for (int mt = 0; mt < 2; ++mt)
#pragma unroll
        for (int r = 0; r < 4; ++r) {
          float v = fmaxf(sv[mt][0][r], sv[mt][1][r]);
          v = fmaxf(v, __shfl_xor(v, 1));
          v = fmaxf(v, __shfl_xor(v, 2));
          v = fmaxf(v, __shfl_xor(v, 4));
          v = fmaxf(v, __shfl_xor(v, 8));
          float mn = fmaxf(mrow[mt][r], v);
          float al = __expf(mrow[mt][r] - mn);
          mrow[mt][r] = mn;
          float sum = 0.f;
#pragma unroll
          for (int n = 0; n < 2; ++n) {
            float p = __expf(sv[mt][n][r] - mn);
            Pw[(mt * 16 + quad * 4 + r) * 40 + n * 16 + m16] = f2h(p);
            sum += p;
          }
          sum += __shfl_xor(sum, 1);
          sum += __shfl_xor(sum, 2);
          sum += __shfl_xor(sum, 4);
          sum += __shfl_xor(sum, 8);
          lrow[mt][r] = lrow[mt][r] * al + sum;
          alv[mt][r] = al;
        }
#pragma unroll
      for (int mt = 0; mt < 2; ++mt)
#pragma unroll
        for (int nb = 0; nb < 16; ++nb)
#pragma unroll
          for (int r = 0; r < 4; ++r) O[mt][nb][r] *= alv[mt][r];
      half8 pf[2];
#pragma unroll
      for (int mt = 0; mt < 2; ++mt)
        pf[mt] = __builtin_bit_cast(
            half8, *(const ushort8*)&Pw[(mt * 16 + m16) * 40 + quad * 8]);
      __builtin_amdgcn_s_setprio(1);
#pragma unroll
      for (int nb = 0; nb < 16; ++nb) {
        const int d = nb * 16 + m16;
        half8 vf = __builtin_bit_cast(
            half8,
            *(const ushort8*)&Vs[d * 32 + ((quad ^ ((d >> 1) & 3)) << 3)]);
        O[0][nb] = __builtin_amdgcn_mfma_f32_16x16x32_f16(pf[0], vf, O[0][nb],
                                                          0, 0, 0);
        O[1][nb] = __builtin_amdgcn_mfma_f32_16x16x32_f16(pf[1], vf, O[1][nb],
                                                          0, 0, 0);
      }
      __builtin_amdgcn_s_setprio(0);
    }
    __syncthreads();  // all V reads done (also drains K DMAs)
    if (more) STAGE_V(kv0 + 128);
    __syncthreads();  // drains V DMAs
  }
#undef STAGE_K
#undef STAGE_V

  // ---- 4-way merge: (grp2,grp3) -> (grp0,grp1), then grp1 -> grp0 ----
  __syncthreads();
  float* OmB = (float*)smem;               // 4 slots x 32x257 f32
  float* mlB = (float*)(smem + 131584);    // 4 slots x 32 x {m,l}
  if (grp >= 2) {
    const int slot = (grp & 1) + 2 * qw;
    float* Om = OmB + slot * 8224;
    float* ml = mlB + slot * 64;
#pragma unroll
    for (int mt = 0; mt < 2; ++mt)
#pragma unroll
      for (int nb = 0; nb < 16; ++nb)
#pragma unroll
        for (int r = 0; r < 4; ++r)
          Om[(mt * 16 + quad * 4 + r) * 257 + nb * 16 + m16] = O[mt][nb][r];
    if (m16 == 0)
#pragma unroll
      for (int mt = 0; mt < 2; ++mt)
#pragma unroll
        for (int r = 0; r < 4; ++r) {
          ml[(mt * 16 + quad * 4 + r) * 2] = mrow[mt][r];
          ml[(mt * 16 + quad * 4 + r) * 2 + 1] = lrow[mt][r];
        }
  }
  __syncthreads();
  if (grp < 2) {
    const int slot = grp + 2 * qw;
    float* Om = OmB + slot * 8224;
    float* ml = mlB + slot * 64;
    float av[2][4], bv[2][4];
#pragma unroll
    for (int mt = 0; mt < 2; ++mt)
#pragma unroll
      for (int r = 0; r < 4; ++r) {
        const int row = mt * 16 + quad * 4 + r;
        float mB = ml[row * 2], lB = ml[row * 2 + 1];
        float m = fmaxf(mrow[mt][r], mB);
        float a = __expf(mrow[mt][r] - m);
        float bb = __expf(mB - m);
        lrow[mt][r] = lrow[mt][r] * a + lB * bb;
        mrow[mt][r] = m;
        av[mt][r] = a;
        bv[mt][r] = bb;
      }
#pragma unroll
    for (int mt = 0; mt < 2; ++mt)
#pragma unroll
      for (int nb = 0; nb < 16; ++nb)
#pragma unroll
        for (int r = 0; r < 4; ++r)
          O[mt][nb][r] =
              O[mt][nb][r] * av[mt][r] +
              Om[(mt * 16 + quad * 4 + r) * 257 + nb * 16 + m16] * bv[mt][r];
  }
  __syncthreads();
  if (grp == 1) {
    const int slot = qw;
    float* Om = OmB + slot * 8224;
    float* ml = mlB + slot * 64;
#pragma unroll
    for (int mt = 0; mt < 2; ++mt)
#pragma unroll
      for (int nb = 0; nb < 16; ++nb)
#pragma unroll
        for (int r = 0; r < 4; ++r)
          Om[(mt * 16 + quad * 4 + r) * 257 + nb * 16 + m16] = O[mt][nb][r];
    if (m16 == 0)
#pragma unroll
      for (int mt = 0; mt < 2; ++mt)
#pragma unroll
        for (int r = 0; r < 4; ++r) {
          ml[(mt * 16 + quad * 4 + r) * 2] = mrow[mt][r];
          ml[(mt * 16 + quad * 4 + r) * 2 + 1] = lrow[mt][r];
        }
  }
  __syncthreads();
  if (grp == 0) {
    const int slot = qw;
    float* Om = OmB + slot * 8224;
    float* ml = mlB + slot * 64;
    float av[2][4], bv[2][4], inv[2][4];
#pragma unroll
    for (int mt = 0; mt < 2; ++mt)
#pragma unroll
      for (int r = 0; r < 4; ++r) {
        const int row = mt * 16 + quad * 4 + r;
        float mB = ml[row * 2], lB = ml[row * 2 + 1];
        float m = fmaxf(mrow[mt][r], mB);
        float a = __expf(mrow[mt][r] - m);
        float bb = __expf(mB - m);
        av[mt][r] = a;
        bv[mt][r] = bb;
        inv[mt][r] = 1.f / (lrow[mt][r] * a + lB * bb);
      }
#pragma unroll
    for (int mt = 0; mt < 2; ++mt)
#pragma unroll
      for (int nb = 0; nb < 16; ++nb)
#pragma unroll
        for (int r = 0; r < 4; ++r) {
          float ob = Om[(mt * 16 + quad * 4 + r) * 257 + nb * 16 + m16];
          out[baseQK + (size_t)(q0 + mt * 16 + quad * 4 + r) * DD + nb * 16 +
              m16] = (O[mt][nb][r] * av[mt][r] + ob * bv[mt][r]) * inv[mt][r];
        }
  }
}

extern "C" void kernel_launch(void* const* d_in, const int* in_sizes, int n_in,
                              void* d_out, int out_size, void* d_ws, size_t ws_size,
                              hipStream_t stream) {
  const float* x = (const float*)d_in[0];
  const float* Wq = (const float*)d_in[1];
  const float* Wk = (const float*)d_in[2];
  const float* Wv = (const float*)d_in[3];
  const int* lens = (const int*)d_in[4];
  unsigned short* Qb = (unsigned short*)d_ws;
  unsigned short* Kb = Qb + (size_t)BB * LL * DD;
  unsigned short* VT = Kb + (size_t)BB * LL * DD;
  unsigned short* Wh = VT + (size_t)BB * LL * DD;
  float* out = (float*)d_out;

  wcvt<<<96, 256, 0, stream>>>(Wq, Wk, Wv, Wh);
  proj<<<512, 256, 0, stream>>>(x, Wh, Qb, Kb, VT);
  attn<<<dim3(8, 32), 512, 0, stream>>>(Qb, Kb, VT, lens, out);
}

// Round 6
// 165.653 us; speedup vs baseline: 1.4221x; 1.4107x over previous
//
#include <hip/hip_runtime.h>

#define BB 8
#define LL 2048
#define DD 256

typedef _Float16 half8 __attribute__((ext_vector_type(8)));
typedef float floatx4 __attribute__((ext_vector_type(4)));
typedef unsigned short ushort8 __attribute__((ext_vector_type(8)));

__device__ inline unsigned short f2h(float f) {
  _Float16 h = (_Float16)f;
  return __builtin_bit_cast(unsigned short, h);
}

#define GLD16(src, ldsbase)                                                    \
  __builtin_amdgcn_global_load_lds(                                           \
      (const __attribute__((address_space(1))) unsigned int*)(src),           \
      (__attribute__((address_space(3))) unsigned int*)(ldsbase), 16, 0, 0)

// ---------------------------------------------------------------------------
// Kernel 0: W fp32 -> fp16, Wh[3][256][256].  grid 96, block 256.
// ---------------------------------------------------------------------------
__global__ __launch_bounds__(256) void wcvt(
    const float* __restrict__ Wq, const float* __restrict__ Wk,
    const float* __restrict__ Wv, unsigned short* __restrict__ Wh) {
  const int bm = blockIdx.x >> 5;
  const float* src = (bm == 0) ? Wq : (bm == 1) ? Wk : Wv;
  const int off = (blockIdx.x & 31) * 2048 + threadIdx.x * 8;
  float4 a = *(const float4*)(src + off);
  float4 b = *(const float4*)(src + off + 4);
  ushort8 u = {f2h(a.x), f2h(a.y), f2h(a.z), f2h(a.w),
               f2h(b.x), f2h(b.y), f2h(b.z), f2h(b.w)};
  *(ushort8*)(Wh + bm * 65536 + off) = u;
}

// ---------------------------------------------------------------------------
// Kernel 1: fused QKV projection, v2.
// The old version loaded W fragments straight from global: 16 lanes at
// 512-B stride = 16 sectors per load instruction, 192 loads/wave, no reuse
// -> VMEM-request-bound (~85us vs ~14us roofline).  Now W is staged per
// 64-row group through LDS via global_load_lds (linear 1KB/instr, source
// chunks pre-swizzled cc^(row&7)), fragments read from LDS (<=2-way).
// LDS 52KB -> 3 blocks/CU so stage drains hide under other blocks.
// ---------------------------------------------------------------------------
__global__ __launch_bounds__(256) void proj(
    const float* __restrict__ x, const unsigned short* __restrict__ Wh,
    unsigned short* __restrict__ Qb, unsigned short* __restrict__ Kb,
    unsigned short* __restrict__ VT) {
  // [0,32768)       Ws: 64 rows x 256 f16, 16B chunk cc stored at cc^(row&7)
  // [32768,53248)   out tile: 10240 ushort (stride 264 for Q/K, 40 for VT)
  __shared__ __attribute__((aligned(16))) unsigned char smem[53248];
  unsigned short* Ws = (unsigned short*)smem;
  unsigned short* tile = (unsigned short*)(smem + 32768);
  const int t = threadIdx.x;
  const int wave = t >> 6, lane = t & 63, quad = lane >> 4, m16 = lane & 15;
  const int l0g = blockIdx.x * 32;
  const int b = l0g >> 11, lb = l0g & 2047;

  // x A-frags (one-time, amortized; 4x wave redundancy absorbed by L1/L2)
  half8 xf[2][8];
#pragma unroll
  for (int mt = 0; mt < 2; ++mt) {
    const float* xp = x + (size_t)(l0g + mt * 16 + m16) * DD + quad * 8;
#pragma unroll
    for (int kb = 0; kb < 8; ++kb) {
      float4 a = *(const float4*)(xp + kb * 32);
      float4 c = *(const float4*)(xp + kb * 32 + 4);
      ushort8 u = {f2h(a.x), f2h(a.y), f2h(a.z), f2h(a.w),
                   f2h(c.x), f2h(c.y), f2h(c.z), f2h(c.w)};
      xf[mt][kb] = __builtin_bit_cast(half8, u);
    }
  }

  // 12 groups: mat = gg>>2, og = gg&3; each group = 64 o-rows (32 KB).
  for (int gg = 0; gg < 12; ++gg) {
    const int mat = gg >> 2, og = gg & 3;
    // stage W group: 2048 chunks, 8 per thread, linear LDS dest,
    // pre-swizzled global source.
#pragma unroll
    for (int c = 0; c < 8; ++c) {
      int ch = c * 256 + t;
      int row = ch >> 5, cc = ch & 31;
      const unsigned short* src = Wh + mat * 65536 +
          (size_t)(og * 64 + row) * DD + ((cc ^ (row & 7)) << 3);
      GLD16(src, smem + (c * 256 + wave * 64) * 16);
    }
    __syncthreads();  // drain DMA

    // wave's o-tile: ot = og*4 + wave; o-row within group = wave*16 + m16
    const int ot = og * 4 + wave;
    const int wrow = wave * 16 + m16;
    floatx4 acc[2] = {{0, 0, 0, 0}, {0, 0, 0, 0}};
    if (mat < 2) {
#pragma unroll
      for (int kb = 0; kb < 8; ++kb) {
        half8 wf = __builtin_bit_cast(
            half8, *(const ushort8*)&Ws[wrow * 256 +
                                        (((kb * 4 + quad) ^ (wrow & 7)) << 3)]);
        acc[0] = __builtin_amdgcn_mfma_f32_16x16x32_f16(xf[0][kb], wf,
                                                        acc[0], 0, 0, 0);
        acc[1] = __builtin_amdgcn_mfma_f32_16x16x32_f16(xf[1][kb], wf,
                                                        acc[1], 0, 0, 0);
      }
#pragma unroll
      for (int mt = 0; mt < 2; ++mt)
#pragma unroll
        for (int r = 0; r < 4; ++r)
          tile[(mt * 16 + quad * 4 + r) * 264 + ot * 16 + m16] =
              f2h(acc[mt][r]);
    } else {
#pragma unroll
      for (int kb = 0; kb < 8; ++kb) {
        half8 wf = __builtin_bit_cast(
            half8, *(const ushort8*)&Ws[wrow * 256 +
                                        (((kb * 4 + quad) ^ (wrow & 7)) << 3)]);
        acc[0] = __builtin_amdgcn_mfma_f32_16x16x32_f16(wf, xf[0][kb],
                                                        acc[0], 0, 0, 0);
        acc[1] = __builtin_amdgcn_mfma_f32_16x16x32_f16(wf, xf[1][kb],
                                                        acc[1], 0, 0, 0);
      }
#pragma unroll
      for (int mt = 0; mt < 2; ++mt)
#pragma unroll
        for (int r = 0; r < 4; ++r)
          tile[(ot * 16 + quad * 4 + r) * 40 + mt * 16 + m16] =
              f2h(acc[mt][r]);
    }
    __syncthreads();  // tile writes done; Ws readers done (safe to restage)

    if (og == 3) {  // mat complete: coalesced global store of the tile
      if (mat < 2) {
        unsigned short* Out = mat ? Kb : Qb;
        const int row = t >> 3, c0 = (t & 7) * 8;
#pragma unroll
        for (int i = 0; i < 4; ++i) {
          ushort8 v = *(const ushort8*)&tile[row * 264 + c0 + i * 64];
          *(ushort8*)(Out + (size_t)(l0g + row) * DD + c0 + i * 64) = v;
        }
      } else {
        const int dd = t >> 2, lc = (t & 3) * 8;
#pragma unroll
        for (int p = 0; p < 4; ++p) {
          const int d = p * 64 + dd;
          ushort8 v = *(const ushort8*)&tile[d * 40 + lc];
          *(ushort8*)(VT + ((size_t)(b * DD + d)) * LL + lb + lc) = v;
        }
      }
      __syncthreads();  // stores read tile before next mat overwrites
    }
  }
}

// ---------------------------------------------------------------------------
// Kernel 2: flash attention — REVERTED to the round-1 version (82.5 us,
// best measured).  512 thr = 8 waves, 2 kv-groups x 4 q-waves, 16 q/wave,
// reg-staged double buffer with pinned issue points, 2-way LDS merge.
// ---------------------------------------------------------------------------
__global__ __launch_bounds__(512, 2) void attn(
    const unsigned short* __restrict__ Qb, const unsigned short* __restrict__ Kb,
    const unsigned short* __restrict__ VT, const int* __restrict__ lens,
    float* __restrict__ out) {
  // [0,65536): Ks (2 grp x 64x256)  [65536,131072): Vs (2 grp x 256x64)
  // [131072,149504): Ps (8 waves x 16x72)
  __shared__ __attribute__((aligned(16))) unsigned char smem[149504];
  const int t = threadIdx.x;
  const int wave = t >> 6, lane = t & 63, quad = lane >> 4, m16 = lane & 15;
  const int grp = wave >> 2, qw = wave & 3, tgl = t & 255;
  unsigned short* Ks = (unsigned short*)(smem + grp * 32768);
  unsigned short* Vs = (unsigned short*)(smem + 65536 + grp * 32768);
  unsigned short* Pw = (unsigned short*)(smem + 131072 + wave * 2304);

  const int b = blockIdx.x;           // batch on x -> XCD affinity
  const int q0 = blockIdx.y * 64;
  const int len = lens[b];
  const size_t baseQK = (size_t)b * LL * DD;
  const size_t baseVT = (size_t)b * DD * LL;

  half8 qf[8];
  {
    const unsigned short* qrow =
        Qb + baseQK + (size_t)(q0 + qw * 16 + m16) * DD + quad * 8;
    for (int kb = 0; kb < 8; ++kb)
      qf[kb] = __builtin_bit_cast(half8, *(const ushort8*)(qrow + kb * 32));
  }

  floatx4 O[16];
  for (int i = 0; i < 16; ++i) O[i] = (floatx4){0, 0, 0, 0};
  float mrow[4] = {-1e30f, -1e30f, -1e30f, -1e30f};
  float lrow[4] = {0.f, 0.f, 0.f, 0.f};

  ushort8 kreg[8], vreg[8];
  const unsigned short* kbase = Kb + baseQK;
  const unsigned short* vbase = VT + baseVT;

#define LOAD_TILES(KV0)                                                      \
  {                                                                          \
    const unsigned short* kp = kbase + (size_t)(KV0)*DD;                     \
    for (int c = 0; c < 8; ++c)                                              \
      kreg[c] = *(const ushort8*)(kp + (tgl + c * 256) * 8);                 \
    for (int c = 0; c < 8; ++c) {                                            \
      int ch = tgl + c * 256;                                                \
      vreg[c] = *(const ushort8*)(vbase + (size_t)(ch >> 3) * LL + (KV0) +   \
                                  (ch & 7) * 8);                             \
    }                                                                        \
  }

  const int T = (len + 127) >> 7;  // uniform trip count, 128 kv per iter
  LOAD_TILES(grp * 64);
  asm volatile("" ::: "memory");  // pin prefetch issue point

  for (int it = 0; it < T; ++it) {
    const int kv0 = it * 128 + grp * 64;
    __syncthreads();
    for (int c = 0; c < 8; ++c) {
      int ch = tgl + c * 256, row = ch >> 5, cc = ch & 31;
      *(ushort8*)&Ks[row * 256 + (cc ^ (row & 7)) * 8] = kreg[c];
    }
    for (int c = 0; c < 8; ++c) {
      int ch = tgl + c * 256, d = ch >> 3, cc = ch & 7;
      *(ushort8*)&Vs[d * 64 + (cc ^ (d & 7)) * 8] = vreg[c];
    }
    __syncthreads();
    if (it + 1 < T) {
      LOAD_TILES(kv0 + 128);
      asm volatile("" ::: "memory");  // keep loads issued here, results live
    }

    if (kv0 < len) {
      // S = Q K^T
      floatx4 s[4];
      for (int n = 0; n < 4; ++n) s[n] = (floatx4){0, 0, 0, 0};
      __builtin_amdgcn_s_setprio(1);
      for (int kb = 0; kb < 8; ++kb)
        for (int n = 0; n < 4; ++n) {
          half8 kf = __builtin_bit_cast(
              half8, *(const ushort8*)&Ks[(n * 16 + m16) * 256 +
                                          (((kb * 4 + quad) ^ (m16 & 7)) * 8)]);
          s[n] = __builtin_amdgcn_mfma_f32_16x16x32_f16(qf[kb], kf, s[n], 0, 0, 0);
        }
      __builtin_amdgcn_s_setprio(0);
      float sv[4][4];
      for (int n = 0; n < 4; ++n) {
        bool valid = (kv0 + n * 16 + m16) < len;
        for (int r = 0; r < 4; ++r)
          sv[n][r] = valid ? s[n][r] * 0.0625f : -1e30f;
      }
      float al[4];
      for (int r = 0; r < 4; ++r) {
        float v = fmaxf(fmaxf(sv[0][r], sv[1][r]), fmaxf(sv[2][r], sv[3][r]));
        v = fmaxf(v, __shfl_xor(v, 1));
        v = fmaxf(v, __shfl_xor(v, 2));
        v = fmaxf(v, __shfl_xor(v, 4));
        v = fmaxf(v, __shfl_xor(v, 8));
        float mn = fmaxf(mrow[r], v);
        al[r] = __expf(mrow[r] - mn);
        mrow[r] = mn;
        float sum = 0.f;
        for (int n = 0; n < 4; ++n) {
          float p = __expf(sv[n][r] - mn);
          Pw[(quad * 4 + r) * 72 + n * 16 + m16] = f2h(p);
          sum += p;
        }
        sum += __shfl_xor(sum, 1);
        sum += __shfl_xor(sum, 2);
        sum += __shfl_xor(sum, 4);
        sum += __shfl_xor(sum, 8);
        lrow[r] = lrow[r] * al[r] + sum;
      }
      for (int i = 0; i < 16; ++i)
        for (int r = 0; r < 4; ++r) O[i][r] *= al[r];
      half8 pf0 = __builtin_bit_cast(half8,
                                     *(const ushort8*)&Pw[m16 * 72 + quad * 8]);
      half8 pf1 = __builtin_bit_cast(
          half8, *(const ushort8*)&Pw[m16 * 72 + 32 + quad * 8]);
      __builtin_amdgcn_s_setprio(1);
      for (int nb = 0; nb < 16; ++nb) {
        half8 vf0 = __builtin_bit_cast(
            half8, *(const ushort8*)&Vs[(nb * 16 + m16) * 64 +
                                        ((quad ^ (m16 & 7)) * 8)]);
        O[nb] = __builtin_amdgcn_mfma_f32_16x16x32_f16(pf0, vf0, O[nb], 0, 0, 0);
        half8 vf1 = __builtin_bit_cast(
            half8, *(const ushort8*)&Vs[(nb * 16 + m16) * 64 +
                                        (((4 + quad) ^ (m16 & 7)) * 8)]);
        O[nb] = __builtin_amdgcn_mfma_f32_16x16x32_f16(pf1, vf1, O[nb], 0, 0, 0);
      }
      __builtin_amdgcn_s_setprio(0);
    }
  }
#undef LOAD_TILES

  // ---- merge group 1 into group 0 via LDS (aliases Ks/Vs region) ----
  __syncthreads();
  float* Om = (float*)(smem) + qw * 4112;       // 16 rows x 257 f32 per wave
  float* ml = (float*)(smem + 65792) + qw * 32; // [2][16] per wave
  if (grp == 1) {
    for (int nb = 0; nb < 16; ++nb)
      for (int r = 0; r < 4; ++r)
        Om[(quad * 4 + r) * 257 + nb * 16 + m16] = O[nb][r];
    if (m16 == 0)
      for (int r = 0; r < 4; ++r) {
        ml[(quad * 4 + r) * 2] = mrow[r];
        ml[(quad * 4 + r) * 2 + 1] = lrow[r];
      }
  }
  __syncthreads();
  if (grp == 0) {
    float a[4], bf[4], inv[4];
    for (int r = 0; r < 4; ++r) {
      float mB = ml[(quad * 4 + r) * 2];
      float lB = ml[(quad * 4 + r) * 2 + 1];
      float m = fmaxf(mrow[r], mB);
      a[r] = __expf(mrow[r] - m);
      bf[r] = __expf(mB - m);
      inv[r] = 1.f / (lrow[r] * a[r] + lB * bf[r]);
    }
    for (int nb = 0; nb < 16; ++nb)
      for (int r = 0; r < 4; ++r) {
        float ob = Om[(quad * 4 + r) * 257 + nb * 16 + m16];
        out[baseQK + (size_t)(q0 + qw * 16 + quad * 4 + r) * DD + nb * 16 +
            m16] = (O[nb][r] * a[r] + ob * bf[r]) * inv[r];
      }
  }
}

extern "C" void kernel_launch(void* const* d_in, const int* in_sizes, int n_in,
                              void* d_out, int out_size, void* d_ws, size_t ws_size,
                              hipStream_t stream) {
  const float* x = (const float*)d_in[0];
  const float* Wq = (const float*)d_in[1];
  const float* Wk = (const float*)d_in[2];
  const float* Wv = (const float*)d_in[3];
  const int* lens = (const int*)d_in[4];
  unsigned short* Qb = (unsigned short*)d_ws;
  unsigned short* Kb = Qb + (size_t)BB * LL * DD;
  unsigned short* VT = Kb + (size_t)BB * LL * DD;
  unsigned short* Wh = VT + (size_t)BB * LL * DD;
  float* out = (float*)d_out;

  wcvt<<<96, 256, 0, stream>>>(Wq, Wk, Wv, Wh);
  proj<<<512, 256, 0, stream>>>(x, Wh, Qb, Kb, VT);
  attn<<<dim3(8, 32), 512, 0, stream>>>(Qb, Kb, VT, lens, out);
}